// Round 10
// baseline (62.004 us; speedup 1.0000x reference)
//
#include <hip/hip_runtime.h>
#include <math.h>

// Problem geometry
#define MTOT  16384      // B*L
#define DM    1024
#define HIDN  128
#define HNB   256
#define NBAT  4
#define CLK   32         // rows per k_mega block == scan chunk
#define NBLK  512        // MTOT/CLK  -> 2 blocks/CU
#define CPB   128        // chunks per batch (4096/32)

typedef _Float16 v8h __attribute__((ext_vector_type(8)));
typedef float    v4f __attribute__((ext_vector_type(4)));
#define MFMA16(a,b,c) __builtin_amdgcn_mfma_f32_16x16x32_f16((a),(b),(c),0,0,0)

// Weight blobs (d_ws when big enough, else out1 region). 64B rows, XOR-swz:
//  W1: 32 k-tiles x 16384 B: {h[col=128][64B] | l @ +8192}, seg s at pos s^(col&3)
//  W2 @524288: 4 k-tiles x 32768 B: {h[col=256][64B] | l @ +16384}
#define W1TILE  16384
#define W2BASE  524288
#define W2TILE  32768
#define BLOB_BYTES 655360

// k_mega LDS map (73728 B -> 2 blocks/CU):
//  raw A fp32 ring: 4 x 4096        @0
//  split Ah dbuf:   2 x 2048        @16384
//  split Al dbuf:   2 x 2048        @20480
//  W1 tri-buffer:   3 x 16384       @24576 .. 73728
//  H (post-GEMM1):  Hh @40960 (8704) | Hl @49664 (8704)   [over dead W1 buf1+]
//  Z (post-GEMM2):  [32][260] f32   @0 (33280)            [over dead raw/split/W1b0]
#define RAWOFF 0
#define AHOFF  16384
#define ALOFF  20480
#define W1OFF  24576
#define HHOFF  40960
#define HLOFF  49664
#define ZOFF   0
#define SMEMSZ 73728

#define VMCNT_(N) asm volatile("s_waitcnt vmcnt(" #N ")" ::: "memory")
#define VMCNT(N) VMCNT_(N)
#define BARRIER() do { asm volatile("s_waitcnt lgkmcnt(0)" ::: "memory"); \
                       __builtin_amdgcn_s_barrier(); } while (0)

typedef const __attribute__((address_space(1))) void* gas1_t;
typedef __attribute__((address_space(3))) void* las3_t;

__device__ __forceinline__ void gld16(const void* g, void* l) {
    __builtin_amdgcn_global_load_lds((gas1_t)g, (las3_t)l, 16, 0, 0);
}

// ---------------------------------------------------------------------------
// K0: weights -> fp16-split blobs, 64B rows, seg s stored at pos s^(col&3).
//     Xh = fp16(x); Xl = fp16((x - Xh) * 4096)
// ---------------------------------------------------------------------------
__global__ __launch_bounds__(256) void k_prep(
    const float* __restrict__ W1,   // [1024][128]
    const float* __restrict__ W2,   // [128][256]
    char* __restrict__ blobs)
{
    __shared__ float lds[32][260];
    const int t = threadIdx.x, blk = blockIdx.x;
    if (blk < 32) {
        const int k0 = blk * 32;
        #pragma unroll
        for (int i = 0; i < 4; ++i) {
            int j = t + i * 256;
            int k = j >> 5, n4 = (j & 31) << 2;
            *(float4*)&lds[k][n4] = *(const float4*)&W1[(size_t)(k0 + k) * HIDN + n4];
        }
        __syncthreads();
        const int n = t >> 1, kh = t & 1;
        #pragma unroll
        for (int si = 0; si < 2; ++si) {
            const int s = 2 * kh + si;
            union { _Float16 h[8]; int4 v; } H, L;
            #pragma unroll
            for (int e = 0; e < 8; ++e) {
                float v = lds[s * 8 + e][n];
                _Float16 hh = (_Float16)v;
                H.h[e] = hh;
                L.h[e] = (_Float16)((v - (float)hh) * 4096.f);
            }
            char* d = blobs + blk * W1TILE + n * 64 + ((s ^ (n & 3)) << 4);
            *(int4*)d = H.v;
            *(int4*)(d + 8192) = L.v;
        }
    } else {
        const int ks = blk - 32, k0 = ks * 32;
        #pragma unroll
        for (int i = 0; i < 8; ++i) {
            int j = t + i * 256;
            int k = j >> 6, n4 = (j & 63) << 2;
            *(float4*)&lds[k][n4] = *(const float4*)&W2[(size_t)(k0 + k) * HNB + n4];
        }
        __syncthreads();
        const int n = t;
        #pragma unroll
        for (int s = 0; s < 4; ++s) {
            union { _Float16 h[8]; int4 v; } H, L;
            #pragma unroll
            for (int e = 0; e < 8; ++e) {
                float v = lds[s * 8 + e][n];
                _Float16 hh = (_Float16)v;
                H.h[e] = hh;
                L.h[e] = (_Float16)((v - (float)hh) * 4096.f);
            }
            char* d = blobs + W2BASE + ks * W2TILE + n * 64 + ((s ^ (n & 3)) << 4);
            *(int4*)d = H.v;
            *(int4*)(d + 16384) = L.v;
        }
    }
}

// ---------------------------------------------------------------------------
// K1: mega. Block = 32 rows = one chunk; 512 thr (8 waves), grid 512 ->
// 2 blocks/CU, 4 waves/SIMD. Wave roles: waves 0-3 stage raw A (dist-4 glds
// ring) + cvt own rows + scan; waves 4-7 stage W1 (tri-buffer, dist-2 glds)
// + fills. GEMM1: wave tile 16x32 (mh=wid>>2, np=wid&3), 32 k-steps, one
// lgkm barrier/step, counted vmcnt (never 0 mid-loop). GEMM2: W2 reg-direct.
// ---------------------------------------------------------------------------
__global__ __launch_bounds__(512, 4) void k_mega(
    const float* __restrict__ A,      // content [16384][1024]
    const float* __restrict__ theta,  // [16384][256]
    const float* __restrict__ b1, const float* __restrict__ b2,
    const float* __restrict__ logPi, const float* __restrict__ logR,
    const char* __restrict__ blobs,
    float* __restrict__ out0, float* __restrict__ out2,
    float* fill1, float* fill3,       // non-null only in ws mode
    float* carry, int cstride)
{
    __shared__ __attribute__((aligned(16))) char smem[SMEMSZ];

    const int tid  = threadIdx.x;
    const int blk  = blockIdx.x;
    const int m0   = blk * CLK;
    const int lane = tid & 63;
    const int wid  = tid >> 6;
    const int ln15 = lane & 15;
    const int q    = lane >> 4;
    const int np   = wid & 3;    // col group (32*np..+31)
    const int mh   = wid >> 2;   // row half (16*mh..+15)

    // ---- raw A staging (waves 0-3: wave w stages rows w*8..+7, 1 glds/step)
    const int rrow = (wid & 3) * 8 + (lane >> 3);
    const float* aStage = A + (size_t)(m0 + rrow) * DM + (lane & 7) * 4;
    const int rawDst = rrow * 128 + (lane & 7) * 16;

    // ---- cvt indices (wave converts its own rows; 4 floats/lane)
    const int crow = (wid & 3) * 8 + (lane >> 3);
    const int cvtRd = crow * 128 + (lane & 7) * 16;
    const int cs = (lane & 7) >> 1, chalf = (lane & 7) & 1;
    const int cvtWr = crow * 64 + ((cs ^ ((crow >> 1) & 3)) << 4) + chalf * 8;

    // ---- W1 staging (waves 4-7: 4 glds/step each, byte-copy of 16KB tile)
    const int wq = wid & 3;
    const char* wSrcB = blobs + wq * 4096 + lane * 16;
    const int   wDstB = wq * 4096 + lane * 16;

    // ---- frag read offsets
    const int arow = 16 * mh + ln15;
    const int aby  = arow * 64 + ((q ^ ((arow >> 1) & 3)) << 4);
    const int col0 = 32 * np + ln15;
    const int col1 = col0 + 16;
    const int wo0  = col0 * 64 + ((q ^ (col0 & 3)) << 4);
    const int wo1  = col1 * 64 + ((q ^ (col1 & 3)) << 4);

    v4f acc1[2], acc2[2];
    acc1[0] = acc1[1] = (v4f){0.f, 0.f, 0.f, 0.f};
    acc2[0] = acc2[1] = (v4f){0.f, 0.f, 0.f, 0.f};

#define CVT(J) do { \
    const char* rb_ = smem + ((J) % 4) * 4096 + cvtRd; \
    v4f rv_ = *(const v4f*)rb_; \
    union { _Float16 h[4]; int2 i; } H_, L_; \
    _Pragma("unroll") \
    for (int e_ = 0; e_ < 4; ++e_) { \
        _Float16 t_ = (_Float16)rv_[e_]; \
        H_.h[e_] = t_; \
        L_.h[e_] = (_Float16)((rv_[e_] - (float)t_) * 4096.f); \
    } \
    *(int2*)(smem + AHOFF + ((J) & 1) * 2048 + cvtWr) = H_.i; \
    *(int2*)(smem + ALOFF + ((J) & 1) * 2048 + cvtWr) = L_.i; \
} while (0)

#define STEP(KT, RVM, WVM, DO_RAW, DO_W, DO_CVT) do { \
    if (wid < 4) { \
        if (DO_RAW) gld16(aStage + (size_t)((KT) + 4) * 32, \
                          smem + ((KT) % 4) * 4096 + rawDst); \
    } else if (DO_W) { \
        const char* ws_ = wSrcB + (size_t)((KT) + 2) * W1TILE; \
        char* wd_ = smem + W1OFF + (((KT) + 2) % 3) * W1TILE + wDstB; \
        gld16(ws_, wd_);                 gld16(ws_ + 1024, wd_ + 1024); \
        gld16(ws_ + 2048, wd_ + 2048);   gld16(ws_ + 3072, wd_ + 3072); \
    } \
    { \
        const char* abH = smem + AHOFF + ((KT) & 1) * 2048; \
        const char* abL = smem + ALOFF + ((KT) & 1) * 2048; \
        const char* wbB = smem + W1OFF + ((KT) % 3) * W1TILE; \
        v8h ah_  = *(const v8h*)(abH + aby); \
        v8h al_  = *(const v8h*)(abL + aby); \
        v8h wh0_ = *(const v8h*)(wbB + wo0); \
        v8h wl0_ = *(const v8h*)(wbB + 8192 + wo0); \
        v8h wh1_ = *(const v8h*)(wbB + wo1); \
        v8h wl1_ = *(const v8h*)(wbB + 8192 + wo1); \
        acc1[0] = MFMA16(ah_, wh0_, acc1[0]); \
        acc2[0] = MFMA16(ah_, wl0_, acc2[0]); \
        acc2[0] = MFMA16(al_, wh0_, acc2[0]); \
        acc1[1] = MFMA16(ah_, wh1_, acc1[1]); \
        acc2[1] = MFMA16(ah_, wl1_, acc2[1]); \
        acc2[1] = MFMA16(al_, wh1_, acc2[1]); \
    } \
    if (wid < 4) { VMCNT(RVM); if (DO_CVT) { CVT((KT) + 1); } } \
    else         { VMCNT(WVM); } \
    BARRIER(); \
} while (0)

    // ---- prologue
    if (wid < 4) {
        gld16(aStage,      smem + 0 * 4096 + rawDst);
        gld16(aStage + 32, smem + 1 * 4096 + rawDst);
        gld16(aStage + 64, smem + 2 * 4096 + rawDst);
        gld16(aStage + 96, smem + 3 * 4096 + rawDst);
        VMCNT(3);
        CVT(0);
    } else {
        #pragma unroll
        for (int t = 0; t < 3; ++t) {
            const char* ws_ = wSrcB + (size_t)t * W1TILE;
            char* wd_ = smem + W1OFF + t * W1TILE + wDstB;
            gld16(ws_, wd_);               gld16(ws_ + 1024, wd_ + 1024);
            gld16(ws_ + 2048, wd_ + 2048); gld16(ws_ + 3072, wd_ + 3072);
        }
        VMCNT(8);
    }
    BARRIER();

    // ---- GEMM1: 32 k-steps
    STEP(0,3,4,1,1,1);  STEP(1,3,4,1,1,1);  STEP(2,3,4,1,1,1);  STEP(3,3,4,1,1,1);
    STEP(4,3,4,1,1,1);  STEP(5,3,4,1,1,1);  STEP(6,3,4,1,1,1);  STEP(7,3,4,1,1,1);
    STEP(8,3,4,1,1,1);  STEP(9,3,4,1,1,1);  STEP(10,3,4,1,1,1); STEP(11,3,4,1,1,1);
    STEP(12,3,4,1,1,1); STEP(13,3,4,1,1,1); STEP(14,3,4,1,1,1); STEP(15,3,4,1,1,1);
    STEP(16,3,4,1,1,1); STEP(17,3,4,1,1,1); STEP(18,3,4,1,1,1); STEP(19,3,4,1,1,1);
    STEP(20,3,4,1,1,1); STEP(21,3,4,1,1,1); STEP(22,3,4,1,1,1); STEP(23,3,4,1,1,1);
    STEP(24,3,4,1,1,1); STEP(25,3,4,1,1,1); STEP(26,3,4,1,1,1); STEP(27,3,4,1,1,1);
    STEP(28,2,4,0,1,1); STEP(29,1,4,0,1,1); STEP(30,0,0,0,0,1); STEP(31,0,0,0,0,0);

    // ---- GELU -> H split into LDS (over dead W1 buf1 region)
    const float inv = 1.f / 4096.f;
    #pragma unroll
    for (int ni = 0; ni < 2; ++ni) {
        const int col = 32 * np + 16 * ni + ln15;
        const float bv = b1[col];
        #pragma unroll
        for (int r = 0; r < 4; ++r) {
            const int row = 16 * mh + 4 * q + r;
            float y = acc1[ni][r] + acc2[ni][r] * inv + bv;
            float h = 0.5f * y * (1.f + erff(y * 0.70710678118654752f));
            _Float16 hh = (_Float16)h;
            _Float16 hl = (_Float16)((h - (float)hh) * 4096.f);
            const int byte_ = row * 272 + ((((col >> 3) ^ ((row >> 1) & 3))) << 4)
                            + (col & 7) * 2;
            *(_Float16*)(smem + HHOFF + byte_) = hh;
            *(_Float16*)(smem + HLOFF + byte_) = hl;
        }
    }
    BARRIER();

    // ---- GEMM2: out 32x256; wave tile 16x64 (mh rows, np -> cols 64np..+63)
    v4f c1[4], c2[4];
    #pragma unroll
    for (int i = 0; i < 4; ++i) {
        c1[i] = (v4f){0.f, 0.f, 0.f, 0.f};
        c2[i] = (v4f){0.f, 0.f, 0.f, 0.f};
    }
    const int hrow = 16 * mh + ln15;
    #pragma unroll
    for (int ks = 0; ks < 4; ++ks) {
        const int hby = hrow * 272 + ((4 * ks + (q ^ ((hrow >> 1) & 3))) << 4);
        v8h hh = *(const v8h*)(smem + HHOFF + hby);
        v8h hl = *(const v8h*)(smem + HLOFF + hby);
        v8h w2h[4], w2l[4];
        #pragma unroll
        for (int ni = 0; ni < 4; ++ni) {
            const int c2i = 64 * np + 16 * ni + ln15;
            const char* wp = blobs + W2BASE + (size_t)ks * W2TILE
                           + c2i * 64 + ((q ^ (c2i & 3)) << 4);
            w2h[ni] = *(const v8h*)(wp);
            w2l[ni] = *(const v8h*)(wp + 16384);
        }
        #pragma unroll
        for (int ni = 0; ni < 4; ++ni) {
            c1[ni] = MFMA16(hh, w2h[ni], c1[ni]);
            c2[ni] = MFMA16(hh, w2l[ni], c2[ni]);
            c2[ni] = MFMA16(hl, w2h[ni], c2[ni]);
        }
    }

    // ---- z = pi*tanh(y2) -> Z LDS (disjoint from H region)
    #pragma unroll
    for (int ni = 0; ni < 4; ++ni) {
        const int col = 64 * np + 16 * ni + ln15;
        const float bv = b2[col];
        #pragma unroll
        for (int r = 0; r < 4; ++r) {
            const int row = 16 * mh + 4 * q + r;
            float y2 = c1[ni][r] + c2[ni][r] * inv + bv;
            *(float*)(smem + ZOFF + row * 1040 + col * 4) =
                3.14159265358979323846f * tanhf(y2);
        }
    }
    BARRIER();

    // ---- scan (waves 0-3) + fills (waves 4-7)
    if (tid < 256) {
        const int c = tid;
        const float Pi = expf(logPi[c]);
        const float Rr = expf(logR[c]);
        const float Kc = Pi / fmaxf(Pi + Rr, 1e-8f);
        const float alpha = 1.f - Kc;
        float d = 0.f;
        float tv[2][16];
        #pragma unroll
        for (int i = 0; i < 16; ++i)
            tv[0][i] = theta[(size_t)(m0 + i) * HNB + c];
        #pragma unroll
        for (int g = 0; g < 2; ++g) {
            if (g < 1) {
                #pragma unroll
                for (int i = 0; i < 16; ++i)
                    tv[1][i] = theta[(size_t)(m0 + 16 + i) * HNB + c];
            }
            float sv[16];
            #pragma unroll
            for (int i = 0; i < 16; ++i) {
                float z = *(const float*)(smem + ZOFF + (g * 16 + i) * 1040 + c * 4);
                float diff = z - tv[g][i];
                float kq = rintf(diff * 0.15915494309189533577f);
                float nu = (float)((double)diff - (double)kq * 6.283185307179586476925286766559);
                d = fmaf(alpha, d, Kc * nu);
                sv[i] = tv[g][i] + d;
            }
            #pragma unroll
            for (int i = 0; i < 16; ++i)
                out0[(size_t)(m0 + g * 16 + i) * HNB + c] = sv[i];
        }
        carry[(size_t)blk * cstride + c] = d;
    } else {
        const int c = tid - 256;
        const float Pi = expf(logPi[c]);
        const float Rr = expf(logR[c]);
        const float Kc = Pi / fmaxf(Pi + Rr, 1e-8f);
        if (fill1) {
            #pragma unroll 4
            for (int i = 0; i < CLK; ++i) {
                size_t idx = (size_t)(m0 + i) * HNB + c;
                out2[idx]  = Kc;
                fill1[idx] = Pi;
                fill3[idx] = Rr;
            }
        } else {
            #pragma unroll 4
            for (int i = 0; i < CLK; ++i)
                out2[(size_t)(m0 + i) * HNB + c] = Kc;
        }
    }
#undef STEP
#undef CVT
}

// ---------------------------------------------------------------------------
// K2: exclusive scan of chunk carries (factor alpha^32), one block per batch.
// ---------------------------------------------------------------------------
__global__ __launch_bounds__(256) void k_cscan(
    const float* __restrict__ logPi, const float* __restrict__ logR,
    float* carry, int cstride)
{
    const int c = threadIdx.x, b = blockIdx.x;
    const float Pi = expf(logPi[c]);
    const float Rr = expf(logR[c]);
    const float alpha = 1.f - Pi / fmaxf(Pi + Rr, 1e-8f);
    float A32 = alpha;
    #pragma unroll
    for (int i = 0; i < 5; ++i) A32 *= A32;   // alpha^32
    float D = 0.f;
    for (int s0 = 0; s0 < CPB; s0 += 16) {
        float a[16];
        #pragma unroll
        for (int j = 0; j < 16; ++j)
            a[j] = carry[(size_t)(b * CPB + s0 + j) * cstride + c];
        #pragma unroll
        for (int j = 0; j < 16; ++j) {
            carry[(size_t)(b * CPB + s0 + j) * cstride + c] = D;
            D = fmaf(A32, D, a[j]);
        }
    }
}

// ---------------------------------------------------------------------------
// K3: out0 += alpha^(i+1)*D; in fallback mode also fills Pi/R.
//     grid 512 = one block per 32-row chunk; D read-before-fill.
// ---------------------------------------------------------------------------
__global__ __launch_bounds__(256) void k_apply(
    const float* __restrict__ logPi, const float* __restrict__ logR,
    float* __restrict__ out0, float* out1, float* out3,
    const float* carry, int cstride, int do_fills)
{
    const int blk = blockIdx.x;
    const int c = threadIdx.x;
    const float Pi = expf(logPi[c]);
    const float Rr = expf(logR[c]);
    const float Kc = Pi / fmaxf(Pi + Rr, 1e-8f);
    const float alpha = 1.f - Kc;
    float D = carry[(size_t)blk * cstride + c];
    float w = alpha * D;
    const size_t base = (size_t)blk * (CLK * HNB) + c;
    if (do_fills) {
        #pragma unroll 4
        for (int i = 0; i < CLK; ++i) {
            size_t idx = base + (size_t)i * HNB;
            out0[idx] += w;
            out1[idx] = Pi;
            out3[idx] = Rr;
            w *= alpha;
        }
    } else {
        #pragma unroll 4
        for (int i = 0; i < CLK; ++i) {
            size_t idx = base + (size_t)i * HNB;
            out0[idx] += w;
            w *= alpha;
        }
    }
}

extern "C" void kernel_launch(void* const* d_in, const int* in_sizes, int n_in,
                              void* d_out, int out_size, void* d_ws, size_t ws_size,
                              hipStream_t stream) {
    const float* theta   = (const float*)d_in[0];
    const float* content = (const float*)d_in[1];
    const float* W1      = (const float*)d_in[2];
    const float* b1      = (const float*)d_in[3];
    const float* W2      = (const float*)d_in[4];
    const float* b2      = (const float*)d_in[5];
    const float* logPi   = (const float*)d_in[6];
    const float* logR    = (const float*)d_in[7];

    float* out  = (float*)d_out;
    float* out0 = out;
    float* out1 = out + (size_t)MTOT * HNB;
    float* out2 = out + (size_t)2 * MTOT * HNB;
    float* out3 = out + (size_t)3 * MTOT * HNB;

    const size_t carry_bytes = (size_t)NBLK * 256 * 4;          // 512 KB
    const size_t need = carry_bytes + BLOB_BYTES;               // ~1.13 MB
    float* carry; int cstride, do_fills; char* blobs;
    float *f1, *f3;
    if (ws_size >= need) {
        carry   = (float*)d_ws;
        cstride = 256;
        blobs   = (char*)d_ws + carry_bytes;
        f1 = out1; f3 = out3; do_fills = 0;
    } else {
        carry   = out3;                 // chunk's own out3 rows (blk*8192)
        cstride = CLK * HNB;            // 8192
        blobs   = (char*)out1;          // blobs live in out1 until k_apply fills
        f1 = nullptr; f3 = nullptr; do_fills = 1;
    }

    hipLaunchKernelGGL(k_prep, dim3(36), dim3(256), 0, stream, W1, W2, blobs);
    hipLaunchKernelGGL(k_mega, dim3(NBLK), dim3(512), 0, stream,
                       content, theta, b1, b2, logPi, logR, blobs,
                       out0, out2, f1, f3, carry, cstride);
    hipLaunchKernelGGL(k_cscan, dim3(NBAT), dim3(256), 0, stream,
                       logPi, logR, carry, cstride);
    hipLaunchKernelGGL(k_apply, dim3(NBLK), dim3(256), 0, stream,
                       logPi, logR, out0, out1, out3, carry, cstride, do_fills);
}